// Round 9
// baseline (115.835 us; speedup 1.0000x reference)
//
#include <hip/hip_runtime.h>
#include <hip/hip_bf16.h>
#include <stdint.h>

// Problem constants (CompressedKVAttention_11708080848911)
#define Bc    4
#define Hc    32
#define HKVc  8
#define QLc   16
#define KVc   8192
#define Dc    128
#define NREPc 4   // H / HKV

typedef short bf16x8 __attribute__((ext_vector_type(8)));
typedef float f32x4  __attribute__((ext_vector_type(4)));
typedef int   i32x4  __attribute__((ext_vector_type(4)));
typedef unsigned short u16x4 __attribute__((ext_vector_type(4)));

__device__ __forceinline__ unsigned short bf16_rne(float f) {
  union { float f; uint32_t u; } c{f};
  uint32_t u = c.u + 0x7FFFu + ((c.u >> 16) & 1u);
  return (unsigned short)(u >> 16);
}
// exact for integer-valued floats in [0,255] (low 16 mantissa bits are zero)
__device__ __forceinline__ short bf16_exact(float f) {
  union { float f; uint32_t u; } c{f};
  return (short)(unsigned short)(c.u >> 16);
}

// ---------------------------------------------------------------------------
// Phase 1: per-(b,g,split) flash partials. KV caches arrive as INT32.
// R8 (R7 was 114us: blocks ~93% stalled, barrier-locked staging section is
// the serializer; VGPR cliff at 128 blocks residency gains):
//  - K now staged RAW int32 via global_load_lds, DOUBLE-buffered. DMA for
//    tile it+1 is issued at the top of compute(it) (other buffer, readers
//    done one barrier ago) and drained by the existing barrier1 -> in-flight
//    for the whole compute phase, 0 VGPR, 0 VALU in the locked section.
//  - Bank swizzle via PRE-SWIZZLED GLOBAL SOURCE (m173): LDS[t][p] holds
//    K[t][p ^ 4*(t&7)] (dword-level XOR, bits 2..4). Read side applies the
//    same involution -> ds_read_b128 ~2-way conflicts (free).
//  - K unpack (int->bf16) moves into the compute phase per wave (the CU is
//    76% idle there; redundancy across 4 waves is paid from stall budget).
//  - Scales preconverted once per 128-token window into LDS (Sl): removes
//    8 per-tile global loads from the tile critical path.
//  - V path unchanged from R7 (reg prefetch -> transposed bf16 Vlds[128][40],
//    token bits 3..4 XOR-swizzled; written in the locked section).
// LDS: Kraw 32KB + V 10KB + P 5KB + Sl 2KB = 50.2KB -> 3 blocks/CU (accepted:
// locked section shrinks instead).
// ---------------------------------------------------------------------------
__global__ __launch_bounds__(256) void attn_partial(
    const float* __restrict__ q, const int* __restrict__ kc,
    const int* __restrict__ vc,
    const float* __restrict__ ksc, const float* __restrict__ kzr,
    const float* __restrict__ vsc, const float* __restrict__ vzr,
    float* __restrict__ ws_acc, float* __restrict__ ws_m,
    float* __restrict__ ws_l, int nsplit)
{
  __shared__ __align__(16) int            Kraw[2][32][128];   // 32 KB raw K
  __shared__ __align__(16) unsigned short Vlds[128][40];      // 10 KB
  __shared__ __align__(16) unsigned short Plds[4][16][40];    // 5 KB
  __shared__ __align__(16) float          Sl[4][128];         // 2 KB scales

  const int bid   = blockIdx.x;
  const int split = bid % nsplit;
  const int bg    = bid / nsplit;          // 0..31  (= b*HKV + g)
  const int chunk = KVc / nsplit;
  const int t_begin = split * chunk;
  const int nt    = chunk >> 5;            // 32-token tiles

  const int tid  = threadIdx.x;
  const int wave = tid >> 6;
  const int lane = tid & 63;
  const int l15  = lane & 15;
  const int lg   = lane >> 4;              // 0..3

  const int b = bg >> 3, g = bg & 7;
  const int h = (g << 2) + wave;           // this wave's query head

  // ---- Q fragments (bf16) + per-row sum of bf16-rounded Q ----
  bf16x8 qa[4];
  float qsum = 0.f;
  const float* qrow = q + ((size_t)((b * Hc + h) * QLc + l15)) * Dc;
#pragma unroll
  for (int ks = 0; ks < 4; ++ks) {
    const float* p = qrow + ks * 32 + (lg << 3);
    bf16x8 f;
#pragma unroll
    for (int j = 0; j < 8; ++j) {
      unsigned short hb = bf16_rne(p[j]);
      f[j] = (short)hb;
      union { uint32_t u; float ff; } w{(uint32_t)hb << 16};
      qsum += w.ff;                        // sum of post-rounding values
    }
    qa[ks] = f;
  }
  qsum += __shfl_xor(qsum, 16);
  qsum += __shfl_xor(qsum, 32);            // every lane: qsum of row (lane&15)
  float qsumc[4];                          // re-map to C-layout rows 4*lg+j
#pragma unroll
  for (int j = 0; j < 4; ++j) qsumc[j] = __shfl(qsum, (lg << 2) + j);

  const float QK_SCALE = 0.088388347648f * 1.44269504089f; // d^-1/2 * log2(e)

  float m[4], ell[4], corr[4];
  f32x4 acc[8];
#pragma unroll
  for (int j = 0; j < 4; ++j) { m[j] = -1e30f; ell[j] = 0.f; corr[j] = 0.f; }
#pragma unroll
  for (int dt = 0; dt < 8; ++dt) acc[dt] = (f32x4){0.f, 0.f, 0.f, 0.f};

  const int*   kb   = kc  + (size_t)bg * KVc * Dc;
  const int*   vb   = vc  + (size_t)bg * KVc * Dc;
  const float* kscb = ksc + (size_t)bg * KVc;
  const float* kzrb = kzr + (size_t)bg * KVc;
  const float* vscb = vsc + (size_t)bg * KVc;
  const float* vzrb = vzr + (size_t)bg * KVc;

  // V staging coords (4 tokens x 4 d per thread)
  const int tq  = tid >> 5;                // V: token group 0..7
  const int dq  = (tid & 31) << 2;         // V: d base 0,4,...,124
  const int tb  = (tq << 2) ^ ((((dq >> 4) & 3)) << 3);  // swizzled col base

  // K DMA coords: wave w stages rows 8w..8w+7; call n covers rows 8w+2n..+1.
  // Lane j writes LDS dwords (row 8w+2n + (j>>5), col 4*(j&31)..+3); the
  // global source is pre-swizzled: col ^ 4*(row&7).
  const int kq = (lane & 31) << 2;         // dword col base this lane writes

  // K read-side swizzle constants (same involution as the source swizzle)
  const int xz = (l15 >> 1) & 3;           // (X>>3): bits 3..4 of X
  const int x4 = (l15 & 1) << 2;           // X & 4
  const int bz = (lg ^ xz) << 3;           // 8*(lg ^ xz)

  i32x4 vp[4];                             // V prefetch registers

  // ---- prologue: DMA K tile0 -> buf0; stage V tile0; issue vp(1) ----
  {
#pragma unroll
    for (int n = 0; n < 4; ++n) {
      const int tl = (wave << 3) + (n << 1) + (lane >> 5);
      const int* gsrc = kb + (size_t)(t_begin + tl) * Dc + (kq ^ ((tl & 7) << 2));
      __builtin_amdgcn_global_load_lds(
          (const unsigned int*)gsrc,
          (unsigned int*)&Kraw[0][(wave << 3) + (n << 1)][0], 16, 0, 0);
    }
#pragma unroll
    for (int i = 0; i < 4; ++i)
      vp[i] = *(const i32x4*)(vb + (size_t)(t_begin + (tq << 2) + i) * Dc + dq);
#pragma unroll
    for (int j = 0; j < 4; ++j) {
      u16x4 pk;
#pragma unroll
      for (int i = 0; i < 4; ++i)
        pk[i] = (unsigned short)bf16_exact((float)(vp[i][j] + 128));
      *(u16x4*)&Vlds[dq + j][tb] = pk;
    }
    if (nt > 1) {
#pragma unroll
      for (int i = 0; i < 4; ++i)
        vp[i] = *(const i32x4*)(vb + (size_t)(t_begin + 32 + (tq << 2) + i) * Dc + dq);
    }
  }
  // (no explicit barrier: the it==0 scale-stage barrier below covers it)

  for (int it = 0; it < nt; ++it) {
    const int t0 = t_begin + (it << 5);

    // ---- every 128 tokens: (re)stage preconverted scales; barrier also
    //      drains the pending K DMA and makes prologue V writes visible ----
    if ((it & 3) == 0) {
      const int tl = tid & 127;
      int tok = t0 + tl; tok = tok < KVc ? tok : KVc - 1;
      if (tid < 128) {
        Sl[0][tl] = kscb[tok] * QK_SCALE;
        Sl[1][tl] = kzrb[tok] + 128.f;
      } else {
        Sl[2][tl] = vscb[tok];
        Sl[3][tl] = vzrb[tok] + 128.f;
      }
      __syncthreads();
    }

    // ---- issue K DMA for tile it+1 into the other buffer (its readers
    //      finished at barrier1(it-1)); drained by barrier1(it) ----
    if (it + 1 < nt) {
      const int tn = t0 + 32;
      const int buf = (it + 1) & 1;
#pragma unroll
      for (int n = 0; n < 4; ++n) {
        const int tl = (wave << 3) + (n << 1) + (lane >> 5);
        const int* gsrc = kb + (size_t)(tn + tl) * Dc + (kq ^ ((tl & 7) << 2));
        __builtin_amdgcn_global_load_lds(
            (const unsigned int*)gsrc,
            (unsigned int*)&Kraw[buf][(wave << 3) + (n << 1)][0], 16, 0, 0);
      }
    }

    // ---- scales for this tile from LDS (broadcast reads) ----
    const int tw = ((it & 3) << 5);        // token-in-window base
    const float sclA = Sl[0][tw + l15],      sclB = Sl[0][tw + 16 + l15];
    const float kzpA = Sl[1][tw + l15],      kzpB = Sl[1][tw + 16 + l15];
    const float vsA  = Sl[2][tw + l15],      vsB  = Sl[2][tw + 16 + l15];
    const float vzpA = Sl[3][tw + l15],      vzpB = Sl[3][tw + 16 + l15];

    // ---- QK from raw K in LDS (unpack per wave) ----
    const int kbuf = it & 1;
    f32x4 scA = (f32x4){0.f, 0.f, 0.f, 0.f};
    f32x4 scB = (f32x4){0.f, 0.f, 0.f, 0.f};
#pragma unroll
    for (int ks = 0; ks < 4; ++ks) {       // half A: token = l15
      const int* row = &Kraw[kbuf][l15][0];
      const int base = (ks << 5) + bz;
      i32x4 qA = *(const i32x4*)(row + base + x4);
      i32x4 qB = *(const i32x4*)(row + base + (4 ^ x4));
      bf16x8 kf;
#pragma unroll
      for (int j = 0; j < 4; ++j) {
        kf[j]     = bf16_exact((float)qA[j] + 128.f);
        kf[4 + j] = bf16_exact((float)qB[j] + 128.f);
      }
      scA = __builtin_amdgcn_mfma_f32_16x16x32_bf16(qa[ks], kf, scA, 0, 0, 0);
    }
#pragma unroll
    for (int ks = 0; ks < 4; ++ks) {       // half B: token = 16 + l15
      const int* row = &Kraw[kbuf][16 + l15][0];
      const int base = (ks << 5) + bz;
      i32x4 qA = *(const i32x4*)(row + base + x4);
      i32x4 qB = *(const i32x4*)(row + base + (4 ^ x4));
      bf16x8 kf;
#pragma unroll
      for (int j = 0; j < 4; ++j) {
        kf[j]     = bf16_exact((float)qA[j] + 128.f);
        kf[4 + j] = bf16_exact((float)qB[j] + 128.f);
      }
      scB = __builtin_amdgcn_mfma_f32_16x16x32_bf16(qa[ks], kf, scB, 0, 0, 0);
    }

    float s8[2][4];
#pragma unroll
    for (int j = 0; j < 4; ++j) {
      s8[0][j] = sclA * (scA[j] - kzpA * qsumc[j]);
      s8[1][j] = sclB * (scB[j] - kzpB * qsumc[j]);
    }

    // one max update + rescale per 32-token tile
    float tm[4];
#pragma unroll
    for (int j = 0; j < 4; ++j) {
      tm[j] = fmaxf(s8[0][j], s8[1][j]);
      tm[j] = fmaxf(tm[j], __shfl_xor(tm[j], 1));
      tm[j] = fmaxf(tm[j], __shfl_xor(tm[j], 2));
      tm[j] = fmaxf(tm[j], __shfl_xor(tm[j], 4));
      tm[j] = fmaxf(tm[j], __shfl_xor(tm[j], 8));
    }
    bool need = false;
    float cf[4];
#pragma unroll
    for (int j = 0; j < 4; ++j) {
      float nm = fmaxf(m[j], tm[j]);
      cf[j] = exp2f(m[j] - nm);
      need = need || (tm[j] > m[j]);
      m[j] = nm;
    }
    if (__any(need)) {
#pragma unroll
      for (int j = 0; j < 4; ++j) { ell[j] *= cf[j]; corr[j] *= cf[j]; }
#pragma unroll
      for (int dt = 0; dt < 8; ++dt)
#pragma unroll
        for (int j = 0; j < 4; ++j) acc[dt][j] *= cf[j];
    }

    // P (consistent with final m), value_scale folded; write Plds (wave-private)
#pragma unroll
    for (int j = 0; j < 4; ++j) {
      float pA = exp2f(s8[0][j] - m[j]);
      float pB = exp2f(s8[1][j] - m[j]);
      ell[j] += pA + pB;
      unsigned short ra = bf16_rne(pA * vsA);
      unsigned short rb = bf16_rne(pB * vsB);
      union { uint32_t u; float ff; } wa{(uint32_t)ra << 16}, wb{(uint32_t)rb << 16};
      corr[j] += wa.ff * vzpA + wb.ff * vzpB;
      Plds[wave][(lg << 2) + j][l15]      = ra;
      Plds[wave][(lg << 2) + j][16 + l15] = rb;
    }

    // PV for these 32 tokens
    bf16x8 pa = *(const bf16x8*)&Plds[wave][l15][lg << 3];
#pragma unroll
    for (int dt = 0; dt < 8; ++dt) {
      bf16x8 vbf = *(const bf16x8*)
          &Vlds[(dt << 4) + l15][(lg ^ (dt & 3)) << 3];
      acc[dt] = __builtin_amdgcn_mfma_f32_16x16x32_bf16(pa, vbf, acc[dt], 0, 0, 0);
    }

    // ---- locked section: write V(it+1); issue vp(it+2) ----
    if (it + 1 < nt) {
      __syncthreads();                     // readers done; drains K DMA(it+1)
#pragma unroll
      for (int j = 0; j < 4; ++j) {
        u16x4 pk;
#pragma unroll
        for (int i = 0; i < 4; ++i)
          pk[i] = (unsigned short)bf16_exact((float)(vp[i][j] + 128));
        *(u16x4*)&Vlds[dq + j][tb] = pk;
      }
      if (it + 2 < nt) {
        const int tn = t0 + 64;
#pragma unroll
        for (int i = 0; i < 4; ++i)
          vp[i] = *(const i32x4*)(vb + (size_t)(tn + (tq << 2) + i) * Dc + dq);
      }
      __syncthreads();                     // V writes visible
    }
  }

  // ---- final lane reductions over token slots ----
#pragma unroll
  for (int j = 0; j < 4; ++j) {
    ell[j] += __shfl_xor(ell[j], 1);  ell[j] += __shfl_xor(ell[j], 2);
    ell[j] += __shfl_xor(ell[j], 4);  ell[j] += __shfl_xor(ell[j], 8);
    corr[j] += __shfl_xor(corr[j], 1); corr[j] += __shfl_xor(corr[j], 2);
    corr[j] += __shfl_xor(corr[j], 4); corr[j] += __shfl_xor(corr[j], 8);
  }

  const size_t pbase = ((size_t)bg * nsplit + split) * 64;
#pragma unroll
  for (int dt = 0; dt < 8; ++dt)
#pragma unroll
    for (int j = 0; j < 4; ++j) {
      int row = (wave << 4) + (lg << 2) + j;
      int d   = (dt << 4) + l15;
      ws_acc[(pbase + row) * Dc + d] = acc[dt][j] - corr[j];
    }
  if (l15 == 0) {
#pragma unroll
    for (int j = 0; j < 4; ++j) {
      int row = (wave << 4) + (lg << 2) + j;
      ws_m[pbase + row] = m[j];
      ws_l[pbase + row] = ell[j];
    }
  }
}

// ---------------------------------------------------------------------------
// Phase 2: flash-combine partials and normalize. One block per (bg,row).
// ---------------------------------------------------------------------------
__global__ __launch_bounds__(128) void attn_combine(
    const float* __restrict__ ws_acc, const float* __restrict__ ws_m,
    const float* __restrict__ ws_l, float* __restrict__ out, int nsplit)
{
  const int r   = blockIdx.x;      // 0 .. 32*64-1
  const int bg  = r >> 6;
  const int row = r & 63;
  const int d   = threadIdx.x;     // 0..127

  float M = -1e30f;
#pragma unroll 4
  for (int i = 0; i < nsplit; ++i)
    M = fmaxf(M, ws_m[((size_t)bg * nsplit + i) * 64 + row]);
  float L = 0.f, o = 0.f;
#pragma unroll 4
  for (int i = 0; i < nsplit; ++i) {
    size_t pb = ((size_t)bg * nsplit + i) * 64 + row;
    float w = exp2f(ws_m[pb] - M);
    L += ws_l[pb] * w;
    o += ws_acc[pb * Dc + d] * w;
  }
  const int b = bg >> 3, g = bg & 7;
  const int rep = row >> 4, qq = row & 15;
  out[(((size_t)(b * Hc + g * NREPc + rep)) * QLc + qq) * Dc + d] = o / L;
}

extern "C" void kernel_launch(void* const* d_in, const int* in_sizes, int n_in,
                              void* d_out, int out_size, void* d_ws,
                              size_t ws_size, hipStream_t stream) {
  const float* q   = (const float*)d_in[0];
  const int*   kc  = (const int*)d_in[1];   // int8 values promoted to int32
  const int*   vc  = (const int*)d_in[2];
  const float* ksc = (const float*)d_in[3];
  const float* kzr = (const float*)d_in[4];
  const float* vsc = (const float*)d_in[5];
  const float* vzr = (const float*)d_in[6];
  float* out = (float*)d_out;

  int nsplit = 64;                         // 2048 blocks; fallback if ws small
  while (nsplit > 1) {
    size_t need = (size_t)32 * nsplit * 64 * (Dc + 2) * sizeof(float);
    if (need <= ws_size) break;
    nsplit >>= 1;
  }
  float* ws_acc = (float*)d_ws;                             // [32,ns,64,128]
  float* ws_m   = ws_acc + (size_t)32 * nsplit * 64 * Dc;   // [32,ns,64]
  float* ws_l   = ws_m   + (size_t)32 * nsplit * 64;        // [32,ns,64]

  attn_partial<<<dim3(32 * nsplit), dim3(256), 0, stream>>>(
      q, kc, vc, ksc, kzr, vsc, vzr, ws_acc, ws_m, ws_l, nsplit);
  attn_combine<<<dim3(32 * 64), dim3(128), 0, stream>>>(
      ws_acc, ws_m, ws_l, out, nsplit);
}

// Round 10
// 111.078 us; speedup vs baseline: 1.0428x; 1.0428x over previous
//
#include <hip/hip_runtime.h>
#include <hip/hip_bf16.h>
#include <stdint.h>

// Problem constants (CompressedKVAttention_11708080848911)
#define Bc    4
#define Hc    32
#define HKVc  8
#define QLc   16
#define KVc   8192
#define Dc    128
#define NREPc 4   // H / HKV

typedef _Float16 f16x8 __attribute__((ext_vector_type(8)));
typedef float f32x4  __attribute__((ext_vector_type(4)));
typedef int   i32x4  __attribute__((ext_vector_type(4)));
typedef uint32_t u32x2 __attribute__((ext_vector_type(2)));

// Pack two sign-extended-int8 dwords into one half2 = (x0+1152, x1+1152).
// fp16 0x6400|u = 1024+u (u in [0,255] exact); u = byte^0x80 = x+128.
// 3 VALU ops (perm + and + xor) per 2 elements, packing included.
__device__ __forceinline__ uint32_t pk1152(int x0, int x1) {
  return (__builtin_amdgcn_perm((uint32_t)x1, (uint32_t)x0, 0x05040100u)
          & 0x00FF00FFu) ^ 0x64806480u;
}

// ---------------------------------------------------------------------------
// Phase 1: per-(b,g,split) flash partials. KV caches arrive as INT32.
// R9 (R6/R7/R8 all ~112-116us; staging mechanics are NOT the lever; per-tile
// VALU ~2000cy dominated by int->bf16 unpack):
//  - fp16 everywhere: K/V unpacked with the 0x6400-exponent byte-perm trick
//    (3 ops / 2 elems, packed) as (x+1152); dequant algebra identical with
//    zero-point constant 128 -> 1152. mfma_*_f16 (same rate as bf16).
//  - Q in fp16 (more mantissa than bf16 -> accuracy improves), f32x4 loads.
//  - P' scaled by 1024 (P" = p*vs*1024) to stay out of fp16 subnormal/FTZ
//    territory; ws write divides by 1024. corr uses the same rounded P".
// Structure = R7 exactly: single-buffered K/V LDS, 2 barriers/tile, loads for
// tile it+2 issued in the locked section (in flight across barrier + full
// compute of it+1). K swizzle col^((row&7)<<3) both sides; V [d][t] with
// token bits 3..4 XOR (d>>4)&3; Vlds rows padded to 40 cols (read stride 80B).
// ---------------------------------------------------------------------------
__global__ __launch_bounds__(256) void attn_partial(
    const float* __restrict__ q, const int* __restrict__ kc,
    const int* __restrict__ vc,
    const float* __restrict__ ksc, const float* __restrict__ kzr,
    const float* __restrict__ vsc, const float* __restrict__ vzr,
    float* __restrict__ ws_acc, float* __restrict__ ws_m,
    float* __restrict__ ws_l, int nsplit)
{
  __shared__ __align__(16) unsigned short Klds[32][128];   // fp16 bits, 8 KB
  __shared__ __align__(16) unsigned short Vlds[128][40];   // fp16 bits, 10 KB
  __shared__ __align__(16) unsigned short Plds[4][16][40]; // fp16 bits, 5 KB

  const int bid   = blockIdx.x;
  const int split = bid % nsplit;
  const int bg    = bid / nsplit;          // 0..31  (= b*HKV + g)
  const int chunk = KVc / nsplit;
  const int t_begin = split * chunk;
  const int nt    = chunk >> 5;            // 32-token tiles

  const int tid  = threadIdx.x;
  const int wave = tid >> 6;
  const int lane = tid & 63;
  const int l15  = lane & 15;
  const int lg   = lane >> 4;              // 0..3

  const int b = bg >> 3, g = bg & 7;
  const int h = (g << 2) + wave;           // this wave's query head

  // ---- Q fragments (fp16) + per-row sum of fp16-rounded Q ----
  f16x8 qa[4];
  float qsum = 0.f;
  const float* qrow = q + ((size_t)((b * Hc + h) * QLc + l15)) * Dc;
#pragma unroll
  for (int ks = 0; ks < 4; ++ks) {
    const f32x4* qv = (const f32x4*)(qrow + ks * 32 + (lg << 3));
    f32x4 qlo = qv[0], qhi = qv[1];
    f16x8 f;
#pragma unroll
    for (int j = 0; j < 4; ++j) {
      f[j]     = (_Float16)qlo[j];
      f[4 + j] = (_Float16)qhi[j];
      qsum += (float)f[j] + (float)f[4 + j];   // post-rounding values
    }
    qa[ks] = f;
  }
  qsum += __shfl_xor(qsum, 16);
  qsum += __shfl_xor(qsum, 32);            // every lane: qsum of row (lane&15)
  float qsumc[4];                          // re-map to C-layout rows 4*lg+j
#pragma unroll
  for (int j = 0; j < 4; ++j) qsumc[j] = __shfl(qsum, (lg << 2) + j);

  const float QK_SCALE = 0.088388347648f * 1.44269504089f; // d^-1/2 * log2(e)

  float m[4], ell[4], corr[4];
  f32x4 acc[8];
#pragma unroll
  for (int j = 0; j < 4; ++j) { m[j] = -1e30f; ell[j] = 0.f; corr[j] = 0.f; }
#pragma unroll
  for (int dt = 0; dt < 8; ++dt) acc[dt] = (f32x4){0.f, 0.f, 0.f, 0.f};

  const int*   kb   = kc  + (size_t)bg * KVc * Dc;
  const int*   vb   = vc  + (size_t)bg * KVc * Dc;
  const float* kscb = ksc + (size_t)bg * KVc;
  const float* kzrb = kzr + (size_t)bg * KVc;
  const float* vscb = vsc + (size_t)bg * KVc;
  const float* vzrb = vzr + (size_t)bg * KVc;

  // staging coords
  const int kt  = tid >> 3;                // K: token 0..31
  const int kd  = (tid & 7) << 4;          // K: d base 0,16,...,112 (halves)
  const int ksw = (kt & 7) << 3;           // K col swizzle (u16-index XOR)
  const int tq  = tid >> 5;                // V: token group 0..7
  const int dq  = (tid & 31) << 2;         // V: d base 0,4,...,124
  const int tb  = (tq << 2) ^ ((((dq >> 4) & 3)) << 3);  // swizzled col base

  i32x4 kp[4], vp[4];                      // prefetch registers (one set)

  // ---- prologue: load+write tile 0, then issue tile 1 ----
  {
    const int* ksrc = kb + (size_t)(t_begin + kt) * Dc + kd;
#pragma unroll
    for (int i = 0; i < 4; ++i) kp[i] = ((const i32x4*)ksrc)[i];
#pragma unroll
    for (int i = 0; i < 4; ++i)
      vp[i] = *(const i32x4*)(vb + (size_t)(t_begin + (tq << 2) + i) * Dc + dq);

    i32x4 kA, kB;
    kA[0] = (int)pk1152(kp[0][0], kp[0][1]); kA[1] = (int)pk1152(kp[0][2], kp[0][3]);
    kA[2] = (int)pk1152(kp[1][0], kp[1][1]); kA[3] = (int)pk1152(kp[1][2], kp[1][3]);
    kB[0] = (int)pk1152(kp[2][0], kp[2][1]); kB[1] = (int)pk1152(kp[2][2], kp[2][3]);
    kB[2] = (int)pk1152(kp[3][0], kp[3][1]); kB[3] = (int)pk1152(kp[3][2], kp[3][3]);
    *(i32x4*)&Klds[kt][kd ^ ksw]       = kA;
    *(i32x4*)&Klds[kt][(kd + 8) ^ ksw] = kB;
#pragma unroll
    for (int j = 0; j < 4; ++j) {
      u32x2 pk;
      pk[0] = pk1152(vp[0][j], vp[1][j]);
      pk[1] = pk1152(vp[2][j], vp[3][j]);
      *(u32x2*)&Vlds[dq + j][tb] = pk;
    }
    if (nt > 1) {
      const int* ksrc1 = kb + (size_t)(t_begin + 32 + kt) * Dc + kd;
#pragma unroll
      for (int i = 0; i < 4; ++i) kp[i] = ((const i32x4*)ksrc1)[i];
#pragma unroll
      for (int i = 0; i < 4; ++i)
        vp[i] = *(const i32x4*)(vb + (size_t)(t_begin + 32 + (tq << 2) + i) * Dc + dq);
    }
  }
  __syncthreads();

  for (int it = 0; it < nt; ++it) {
    const int t0 = t_begin + (it << 5);

    // ---- compute tile from LDS (loads for it+1 in flight) ----
    const int tA = t0 + l15, tB = t0 + 16 + l15;
    const float ksA = kscb[tA], kzA = kzrb[tA], vsA = vscb[tA], vzA = vzrb[tA];
    const float ksB = kscb[tB], kzB = kzrb[tB], vsB = vscb[tB], vzB = vzrb[tB];

    f32x4 scA = (f32x4){0.f, 0.f, 0.f, 0.f};
    f32x4 scB = (f32x4){0.f, 0.f, 0.f, 0.f};
#pragma unroll
    for (int ks = 0; ks < 4; ++ks) {
      f16x8 kfA = *(const f16x8*)
          &Klds[l15][(ks * 32 + (lg << 3)) ^ ((l15 & 7) << 3)];
      scA = __builtin_amdgcn_mfma_f32_16x16x32_f16(qa[ks], kfA, scA, 0, 0, 0);
    }
#pragma unroll
    for (int ks = 0; ks < 4; ++ks) {
      f16x8 kfB = *(const f16x8*)
          &Klds[16 + l15][(ks * 32 + (lg << 3)) ^ ((l15 & 7) << 3)];
      scB = __builtin_amdgcn_mfma_f32_16x16x32_f16(qa[ks], kfB, scB, 0, 0, 0);
    }

    float s8[2][4];
    const float sclA = ksA * QK_SCALE, kzpA = kzA + 1152.f;
    const float sclB = ksB * QK_SCALE, kzpB = kzB + 1152.f;
#pragma unroll
    for (int j = 0; j < 4; ++j) {
      s8[0][j] = sclA * (scA[j] - kzpA * qsumc[j]);
      s8[1][j] = sclB * (scB[j] - kzpB * qsumc[j]);
    }

    // one max update + rescale per 32-token tile
    float tm[4];
#pragma unroll
    for (int j = 0; j < 4; ++j) {
      tm[j] = fmaxf(s8[0][j], s8[1][j]);
      tm[j] = fmaxf(tm[j], __shfl_xor(tm[j], 1));
      tm[j] = fmaxf(tm[j], __shfl_xor(tm[j], 2));
      tm[j] = fmaxf(tm[j], __shfl_xor(tm[j], 4));
      tm[j] = fmaxf(tm[j], __shfl_xor(tm[j], 8));
    }
    bool need = false;
    float cf[4];
#pragma unroll
    for (int j = 0; j < 4; ++j) {
      float nm = fmaxf(m[j], tm[j]);
      cf[j] = exp2f(m[j] - nm);
      need = need || (tm[j] > m[j]);
      m[j] = nm;
    }
    if (__any(need)) {
#pragma unroll
      for (int j = 0; j < 4; ++j) { ell[j] *= cf[j]; corr[j] *= cf[j]; }
#pragma unroll
      for (int dt = 0; dt < 8; ++dt)
#pragma unroll
        for (int j = 0; j < 4; ++j) acc[dt][j] *= cf[j];
    }

    // P" = p*vs*1024 (fp16, out of subnormal range); corr uses ROUNDED P"
    const float vsA1k = vsA * 1024.f, vzpA = vzA + 1152.f;
    const float vsB1k = vsB * 1024.f, vzpB = vzB + 1152.f;
#pragma unroll
    for (int j = 0; j < 4; ++j) {
      float pA = exp2f(s8[0][j] - m[j]);
      float pB = exp2f(s8[1][j] - m[j]);
      ell[j] += pA + pB;
      union { _Float16 h; unsigned short u; } ca, cb;
      ca.h = (_Float16)(pA * vsA1k);
      cb.h = (_Float16)(pB * vsB1k);
      corr[j] += (float)ca.h * vzpA + (float)cb.h * vzpB;
      Plds[wave][(lg << 2) + j][l15]      = ca.u;
      Plds[wave][(lg << 2) + j][16 + l15] = cb.u;
    }

    // PV for these 32 tokens
    f16x8 pa = *(const f16x8*)&Plds[wave][l15][lg << 3];
#pragma unroll
    for (int dt = 0; dt < 8; ++dt) {
      f16x8 vbf = *(const f16x8*)
          &Vlds[(dt << 4) + l15][(lg ^ (dt & 3)) << 3];
      acc[dt] = __builtin_amdgcn_mfma_f32_16x16x32_f16(pa, vbf, acc[dt], 0, 0, 0);
    }

    // ---- single-buffer swap: write it+1, issue it+2 ----
    if (it + 1 < nt) {
      __syncthreads();                     // everyone done READING K/V
      i32x4 kA, kB;                        // vmcnt drain for kp/vp here
      kA[0] = (int)pk1152(kp[0][0], kp[0][1]); kA[1] = (int)pk1152(kp[0][2], kp[0][3]);
      kA[2] = (int)pk1152(kp[1][0], kp[1][1]); kA[3] = (int)pk1152(kp[1][2], kp[1][3]);
      kB[0] = (int)pk1152(kp[2][0], kp[2][1]); kB[1] = (int)pk1152(kp[2][2], kp[2][3]);
      kB[2] = (int)pk1152(kp[3][0], kp[3][1]); kB[3] = (int)pk1152(kp[3][2], kp[3][3]);
      *(i32x4*)&Klds[kt][kd ^ ksw]       = kA;
      *(i32x4*)&Klds[kt][(kd + 8) ^ ksw] = kB;
#pragma unroll
      for (int j = 0; j < 4; ++j) {
        u32x2 pk;
        pk[0] = pk1152(vp[0][j], vp[1][j]);
        pk[1] = pk1152(vp[2][j], vp[3][j]);
        *(u32x2*)&Vlds[dq + j][tb] = pk;
      }
      if (it + 2 < nt) {                   // re-issue into freed regs:
        const int tn = t0 + 64;            // in flight across barrier+compute
        const int* ksrc = kb + (size_t)(tn + kt) * Dc + kd;
#pragma unroll
        for (int i = 0; i < 4; ++i) kp[i] = ((const i32x4*)ksrc)[i];
#pragma unroll
        for (int i = 0; i < 4; ++i)
          vp[i] = *(const i32x4*)(vb + (size_t)(tn + (tq << 2) + i) * Dc + dq);
      }
      __syncthreads();                     // writes visible
    }
  }

  // ---- final lane reductions over token slots ----
#pragma unroll
  for (int j = 0; j < 4; ++j) {
    ell[j] += __shfl_xor(ell[j], 1);  ell[j] += __shfl_xor(ell[j], 2);
    ell[j] += __shfl_xor(ell[j], 4);  ell[j] += __shfl_xor(ell[j], 8);
    corr[j] += __shfl_xor(corr[j], 1); corr[j] += __shfl_xor(corr[j], 2);
    corr[j] += __shfl_xor(corr[j], 4); corr[j] += __shfl_xor(corr[j], 8);
  }

  const size_t pbase = ((size_t)bg * nsplit + split) * 64;
  const float inv1k = 0.0009765625f;       // 1/1024 (undo P" scaling)
#pragma unroll
  for (int dt = 0; dt < 8; ++dt)
#pragma unroll
    for (int j = 0; j < 4; ++j) {
      int row = (wave << 4) + (lg << 2) + j;
      int d   = (dt << 4) + l15;
      ws_acc[(pbase + row) * Dc + d] = (acc[dt][j] - corr[j]) * inv1k;
    }
  if (l15 == 0) {
#pragma unroll
    for (int j = 0; j < 4; ++j) {
      int row = (wave << 4) + (lg << 2) + j;
      ws_m[pbase + row] = m[j];
      ws_l[pbase + row] = ell[j];
    }
  }
}

// ---------------------------------------------------------------------------
// Phase 2: flash-combine partials and normalize. One block per (bg,row).
// ---------------------------------------------------------------------------
__global__ __launch_bounds__(128) void attn_combine(
    const float* __restrict__ ws_acc, const float* __restrict__ ws_m,
    const float* __restrict__ ws_l, float* __restrict__ out, int nsplit)
{
  const int r   = blockIdx.x;      // 0 .. 32*64-1
  const int bg  = r >> 6;
  const int row = r & 63;
  const int d   = threadIdx.x;     // 0..127

  float M = -1e30f;
#pragma unroll 4
  for (int i = 0; i < nsplit; ++i)
    M = fmaxf(M, ws_m[((size_t)bg * nsplit + i) * 64 + row]);
  float L = 0.f, o = 0.f;
#pragma unroll 4
  for (int i = 0; i < nsplit; ++i) {
    size_t pb = ((size_t)bg * nsplit + i) * 64 + row;
    float w = exp2f(ws_m[pb] - M);
    L += ws_l[pb] * w;
    o += ws_acc[pb * Dc + d] * w;
  }
  const int b = bg >> 3, g = bg & 7;
  const int rep = row >> 4, qq = row & 15;
  out[(((size_t)(b * Hc + g * NREPc + rep)) * QLc + qq) * Dc + d] = o / L;
}

extern "C" void kernel_launch(void* const* d_in, const int* in_sizes, int n_in,
                              void* d_out, int out_size, void* d_ws,
                              size_t ws_size, hipStream_t stream) {
  const float* q   = (const float*)d_in[0];
  const int*   kc  = (const int*)d_in[1];   // int8 values promoted to int32
  const int*   vc  = (const int*)d_in[2];
  const float* ksc = (const float*)d_in[3];
  const float* kzr = (const float*)d_in[4];
  const float* vsc = (const float*)d_in[5];
  const float* vzr = (const float*)d_in[6];
  float* out = (float*)d_out;

  int nsplit = 64;                         // 2048 blocks; fallback if ws small
  while (nsplit > 1) {
    size_t need = (size_t)32 * nsplit * 64 * (Dc + 2) * sizeof(float);
    if (need <= ws_size) break;
    nsplit >>= 1;
  }
  float* ws_acc = (float*)d_ws;                             // [32,ns,64,128]
  float* ws_m   = ws_acc + (size_t)32 * nsplit * 64 * Dc;   // [32,ns,64]
  float* ws_l   = ws_m   + (size_t)32 * nsplit * 64;        // [32,ns,64]

  attn_partial<<<dim3(32 * nsplit), dim3(256), 0, stream>>>(
      q, kc, vc, ksc, kzr, vsc, vzr, ws_acc, ws_m, ws_l, nsplit);
  attn_combine<<<dim3(32 * 64), dim3(128), 0, stream>>>(
      ws_acc, ws_m, ws_l, out, nsplit);
}